// Round 1
// baseline (592.556 us; speedup 1.0000x reference)
//
#include <hip/hip_runtime.h>
#include <hip/hip_bf16.h>
#include <math.h>

#define BATCH 4
#define T 4096
#define DIN 512
#define D 64
#define SCALE 0.125f
#define NEG_INF -1e30f

// ---------------------------------------------------------------------------
// QKV projection: out[16384][64] = x[16384][512] @ W[512][64], mid weights for
// all rows (edge rows fixed up by fixup_kernel). One block = 64 rows x 64 cols,
// blockIdx.y selects q/k/v. 256 threads, 4x4 micro-tile, rows strided by 16
// (2-way LDS banking = free), W staged transposed for wave-broadcast reads.
// ---------------------------------------------------------------------------
__global__ __launch_bounds__(256, 2) void proj_kernel(
    const float* __restrict__ x,
    const float* __restrict__ Wq, const float* __restrict__ Wk, const float* __restrict__ Wv,
    float* __restrict__ qb, float* __restrict__ kb, float* __restrict__ vb)
{
    __shared__ float Xs[64][36];   // 64 rows x 32 k-cols (+4 pad, float4-aligned)
    __shared__ float Wtt[64][36];  // transposed: [col][k]
    const int mb = blockIdx.x;     // 0..255 (row tiles)
    const int z  = blockIdx.y;     // 0:q 1:k 2:v
    const float* W = (z == 0) ? Wq : (z == 1) ? Wk : Wv;
    float* out     = (z == 0) ? qb : (z == 1) ? kb : vb;
    const int tid = threadIdx.x;
    const int tx = tid & 15;       // row group
    const int ty = tid >> 4;       // col group
    float acc[4][4] = {};

    for (int ks = 0; ks < 16; ++ks) {
        const int kk = ks * 32;
        __syncthreads();
        // stage X tile (64x32) as float4
        #pragma unroll
        for (int it = 0; it < 2; ++it) {
            int idx = it * 256 + tid;
            int r = idx >> 3, c4 = idx & 7;
            float4 val = *(const float4*)(x + (size_t)(mb * 64 + r) * DIN + kk + c4 * 4);
            *(float4*)&Xs[r][c4 * 4] = val;
        }
        // stage W tile transposed (32x64 -> [64][32])
        #pragma unroll
        for (int it = 0; it < 2; ++it) {
            int idx = it * 256 + tid;
            int dd = idx >> 4, c4 = idx & 15;
            float4 val = *(const float4*)(W + (size_t)(kk + dd) * D + c4 * 4);
            Wtt[c4 * 4 + 0][dd] = val.x;
            Wtt[c4 * 4 + 1][dd] = val.y;
            Wtt[c4 * 4 + 2][dd] = val.z;
            Wtt[c4 * 4 + 3][dd] = val.w;
        }
        __syncthreads();
        #pragma unroll
        for (int d4 = 0; d4 < 8; ++d4) {
            float4 xr[4], wc[4];
            #pragma unroll
            for (int i = 0; i < 4; ++i) xr[i] = *(const float4*)&Xs[tx + 16 * i][d4 * 4];
            #pragma unroll
            for (int j = 0; j < 4; ++j) wc[j] = *(const float4*)&Wtt[ty * 4 + j][d4 * 4];
            #pragma unroll
            for (int i = 0; i < 4; ++i)
                #pragma unroll
                for (int j = 0; j < 4; ++j)
                    acc[i][j] += xr[i].x * wc[j].x + xr[i].y * wc[j].y
                               + xr[i].z * wc[j].z + xr[i].w * wc[j].w;
        }
    }
    #pragma unroll
    for (int i = 0; i < 4; ++i) {
        float4 o = make_float4(acc[i][0], acc[i][1], acc[i][2], acc[i][3]);
        *(float4*)(out + (size_t)(mb * 64 + tx + 16 * i) * D + ty * 4) = o;
    }
}

// ---------------------------------------------------------------------------
// Fixup: recompute the 16 edge rows per batch (t<8 or t>=4088) with _s weights.
// Tiny (64 rows x 192 cols x 512 MAC).
// ---------------------------------------------------------------------------
__global__ void fixup_kernel(
    const float* __restrict__ x,
    const float* __restrict__ Wqs, const float* __restrict__ Wks, const float* __restrict__ Wvs,
    float* __restrict__ qb, float* __restrict__ kb, float* __restrict__ vb)
{
    const int b = blockIdx.x, z = blockIdx.y;
    const float* W = (z == 0) ? Wqs : (z == 1) ? Wks : Wvs;
    float* out     = (z == 0) ? qb : (z == 1) ? kb : vb;
    const int tid = threadIdx.x;
    #pragma unroll
    for (int k = 0; k < 4; ++k) {
        int idx = tid + k * 256;
        int r = idx >> 6, col = idx & 63;
        int t = (r < 8) ? r : (4080 + r);           // 8..15 -> 4088..4095
        const float* xrow = x + ((size_t)b * T + t) * DIN;
        float s = 0.f;
        for (int d = 0; d < DIN; ++d) s += xrow[d] * W[d * D + col];
        out[((size_t)b * T + t) * D + col] = s;
    }
}

// ---------------------------------------------------------------------------
// Flash attention (fp32, causal). Block = (batch, q-block of 64, half of KV
// range). 256 threads, 4x4 micro-tiles (rows strided by 16). Online softmax.
// Writes unnormalized partial O + per-row (m, l); merge_kernel combines halves.
// ---------------------------------------------------------------------------
__global__ __launch_bounds__(256, 2) void flash_kernel(
    const float* __restrict__ qbuf, const float* __restrict__ kbuf, const float* __restrict__ vbuf,
    float* __restrict__ Opart, float* __restrict__ mpart, float* __restrict__ lpart)
{
    __shared__ float Qs[64][68];
    __shared__ float Ks[64][68];
    __shared__ float Vt[64][68];   // transposed V: [vdim][key]
    __shared__ float Ss[64][68];   // scores -> P
    __shared__ float mrow[64], lrow[64], arow[64];

    const int bb = blockIdx.y;
    int qb = blockIdx.x >> 1;
    const int h = blockIdx.x & 1;
    if (bb >= 2) qb = 63 - qb;     // pair heavy+light across co-resident blocks
    const int tid = threadIdx.x;
    const int tx = tid & 15, ty = tid >> 4;

    const int nt = qb + 1;          // KV tiles for this q-block
    const int n0 = (nt + 1) >> 1;   // first half size
    const int kb_lo = h ? n0 : 0;
    const int kb_hi = h ? nt : n0;

    const size_t base = (size_t)bb * T * D;
    // stage Q (pre-scaled)
    #pragma unroll
    for (int it = 0; it < 4; ++it) {
        int idx = it * 256 + tid;
        int r = idx >> 4, c4 = idx & 15;
        float4 val = *(const float4*)(qbuf + base + (size_t)(qb * 64 + r) * D + c4 * 4);
        val.x *= SCALE; val.y *= SCALE; val.z *= SCALE; val.w *= SCALE;
        *(float4*)&Qs[r][c4 * 4] = val;
    }
    if (tid < 64) { mrow[tid] = NEG_INF; lrow[tid] = 0.f; }
    float oacc[4][4] = {};
    __syncthreads();

    for (int kb = kb_lo; kb < kb_hi; ++kb) {
        // stage K (row-major) and V (transposed)
        #pragma unroll
        for (int it = 0; it < 4; ++it) {
            int idx = it * 256 + tid;
            int r = idx >> 4, c4 = idx & 15;
            float4 kv = *(const float4*)(kbuf + base + (size_t)(kb * 64 + r) * D + c4 * 4);
            *(float4*)&Ks[r][c4 * 4] = kv;
            float4 vv = *(const float4*)(vbuf + base + (size_t)(kb * 64 + r) * D + c4 * 4);
            Vt[c4 * 4 + 0][r] = vv.x;
            Vt[c4 * 4 + 1][r] = vv.y;
            Vt[c4 * 4 + 2][r] = vv.z;
            Vt[c4 * 4 + 3][r] = vv.w;
        }
        __syncthreads();

        // GEMM1: S = Q @ K^T (Q pre-scaled)
        float sacc[4][4] = {};
        #pragma unroll
        for (int d4 = 0; d4 < 16; ++d4) {
            float4 xr[4], kv[4];
            #pragma unroll
            for (int i = 0; i < 4; ++i) xr[i] = *(const float4*)&Qs[tx + 16 * i][d4 * 4];
            #pragma unroll
            for (int j = 0; j < 4; ++j) kv[j] = *(const float4*)&Ks[ty * 4 + j][d4 * 4];
            #pragma unroll
            for (int i = 0; i < 4; ++i)
                #pragma unroll
                for (int j = 0; j < 4; ++j)
                    sacc[i][j] += xr[i].x * kv[j].x + xr[i].y * kv[j].y
                                + xr[i].z * kv[j].z + xr[i].w * kv[j].w;
        }
        const bool diag = (kb == qb);
        #pragma unroll
        for (int i = 0; i < 4; ++i) {
            int q = tx + 16 * i;
            #pragma unroll
            for (int j = 0; j < 4; ++j) {
                int kc = ty * 4 + j;
                float s = sacc[i][j];
                if (diag && kc > q) s = NEG_INF;
                Ss[q][kc] = s;
            }
        }
        __syncthreads();

        // online softmax row stats: 4 lanes per row
        {
            int row = tid >> 2, seg = tid & 3;
            float vals[16];
            float mx = NEG_INF;
            #pragma unroll
            for (int e = 0; e < 16; ++e) { vals[e] = Ss[row][seg * 16 + e]; mx = fmaxf(mx, vals[e]); }
            mx = fmaxf(mx, __shfl_xor(mx, 1));
            mx = fmaxf(mx, __shfl_xor(mx, 2));
            float mprev = mrow[row];
            float mnew = fmaxf(mprev, mx);
            float sum = 0.f;
            #pragma unroll
            for (int e = 0; e < 16; ++e) {
                float p = __expf(vals[e] - mnew);
                Ss[row][seg * 16 + e] = p;
                sum += p;
            }
            sum += __shfl_xor(sum, 1);
            sum += __shfl_xor(sum, 2);
            if (seg == 0) {
                float alpha = __expf(mprev - mnew);
                arow[row] = alpha;
                lrow[row] = lrow[row] * alpha + sum;
                mrow[row] = mnew;
            }
        }
        __syncthreads();

        // rescale O, then GEMM2: O += P @ V
        float al[4];
        #pragma unroll
        for (int i = 0; i < 4; ++i) al[i] = arow[tx + 16 * i];
        #pragma unroll
        for (int i = 0; i < 4; ++i)
            #pragma unroll
            for (int j = 0; j < 4; ++j) oacc[i][j] *= al[i];
        #pragma unroll
        for (int k4 = 0; k4 < 16; ++k4) {
            float4 pr[4], vc[4];
            #pragma unroll
            for (int i = 0; i < 4; ++i) pr[i] = *(const float4*)&Ss[tx + 16 * i][k4 * 4];
            #pragma unroll
            for (int j = 0; j < 4; ++j) vc[j] = *(const float4*)&Vt[ty * 4 + j][k4 * 4];
            #pragma unroll
            for (int i = 0; i < 4; ++i)
                #pragma unroll
                for (int j = 0; j < 4; ++j)
                    oacc[i][j] += pr[i].x * vc[j].x + pr[i].y * vc[j].y
                                + pr[i].z * vc[j].z + pr[i].w * vc[j].w;
        }
        __syncthreads();  // protect Ss/Ks/Vt before next tile staging
    }

    const int pidx = (bb * 64 + qb) * 2 + h;
    float* Op = Opart + (size_t)pidx * 4096;
    #pragma unroll
    for (int i = 0; i < 4; ++i) {
        float4 o = make_float4(oacc[i][0], oacc[i][1], oacc[i][2], oacc[i][3]);
        *(float4*)(Op + (tx + 16 * i) * 64 + ty * 4) = o;
    }
    if (tid < 64) { mpart[pidx * 64 + tid] = mrow[tid]; lpart[pidx * 64 + tid] = lrow[tid]; }
}

// ---------------------------------------------------------------------------
// Merge the two KV-halves of each q-block and normalize.
// ---------------------------------------------------------------------------
__global__ void merge_kernel(
    const float* __restrict__ Opart, const float* __restrict__ mpart,
    const float* __restrict__ lpart, float* __restrict__ out)
{
    __shared__ float w0s[64], w1s[64];
    const int qb = blockIdx.x, bb = blockIdx.y;
    const int p0 = (bb * 64 + qb) * 2, p1 = p0 + 1;
    const int tid = threadIdx.x;
    if (tid < 64) {
        float m0 = mpart[p0 * 64 + tid], m1 = mpart[p1 * 64 + tid];
        float l0 = lpart[p0 * 64 + tid], l1 = lpart[p1 * 64 + tid];
        float m = fmaxf(m0, m1);
        float w0 = __expf(m0 - m), w1 = __expf(m1 - m);  // empty half: m=-1e30 -> w=0
        float L = l0 * w0 + l1 * w1;
        float inv = 1.0f / L;
        w0s[tid] = w0 * inv; w1s[tid] = w1 * inv;
    }
    __syncthreads();
    const float* O0 = Opart + (size_t)p0 * 4096;
    const float* O1 = Opart + (size_t)p1 * 4096;
    float* dst = out + ((size_t)bb * T + qb * 64) * D;
    #pragma unroll
    for (int k = 0; k < 16; ++k) {
        int e = tid + k * 256;
        int row = e >> 6;
        dst[e] = O0[e] * w0s[row] + O1[e] * w1s[row];
    }
}

extern "C" void kernel_launch(void* const* d_in, const int* in_sizes, int n_in,
                              void* d_out, int out_size, void* d_ws, size_t ws_size,
                              hipStream_t stream) {
    const float* x   = (const float*)d_in[0];
    const float* Wq  = (const float*)d_in[1];
    const float* Wk  = (const float*)d_in[2];
    const float* Wv  = (const float*)d_in[3];
    const float* Wqs = (const float*)d_in[4];
    const float* Wks = (const float*)d_in[5];
    const float* Wvs = (const float*)d_in[6];
    float* out = (float*)d_out;

    char* ws = (char*)d_ws;
    float* qb    = (float*)(ws);                                   // 4 MB
    float* kb    = (float*)(ws + (size_t)4 * 1024 * 1024);         // 4 MB
    float* vb    = (float*)(ws + (size_t)8 * 1024 * 1024);         // 4 MB
    float* Opart = (float*)(ws + (size_t)12 * 1024 * 1024);        // 8 MB (512 x 64 x 64)
    float* mpart = (float*)(ws + (size_t)20 * 1024 * 1024);        // 128 KB
    float* lpart = (float*)(ws + (size_t)20 * 1024 * 1024 + 128 * 1024);

    proj_kernel <<<dim3(256, 3), 256, 0, stream>>>(x, Wq, Wk, Wv, qb, kb, vb);
    fixup_kernel<<<dim3(4, 3),   256, 0, stream>>>(x, Wqs, Wks, Wvs, qb, kb, vb);
    flash_kernel<<<dim3(128, 4), 256, 0, stream>>>(qb, kb, vb, Opart, mpart, lpart);
    merge_kernel<<<dim3(64, 4),  256, 0, stream>>>(Opart, mpart, lpart, out);
}

// Round 2
// 244.745 us; speedup vs baseline: 2.4211x; 2.4211x over previous
//
#include <hip/hip_runtime.h>
#include <hip/hip_bf16.h>

typedef unsigned short u16;
typedef __attribute__((ext_vector_type(8))) short short8;
typedef __attribute__((ext_vector_type(16))) float f32x16;

#define MFMA(A,B,C) __builtin_amdgcn_mfma_f32_32x32x16_bf16(A,B,C,0,0,0)
#define NEG_INF -1e30f

// pack two f32 -> one dword of 2 bf16 (RNE); no builtin on gfx950 (guide T12)
__device__ __forceinline__ unsigned cvtpk_bf16(float a, float b) {
    unsigned r;
    asm("v_cvt_pk_bf16_f32 %0, %1, %2" : "=v"(r) : "v"(a), "v"(b));
    return r;
}
// swap a's high 32 lanes with b's low 32 lanes:
// a' = [a_lo | b_lo], b' = [a_hi | b_hi]
__device__ __forceinline__ void permswap(unsigned &a, unsigned &b) {
    auto r = __builtin_amdgcn_permlane32_swap(a, b, false, false);
    a = r[0]; b = r[1];
}
union W4u { unsigned u[4]; short8 v; };
__device__ __forceinline__ short8 mk8(unsigned a, unsigned b, unsigned c, unsigned d) {
    W4u w; w.u[0] = a; w.u[1] = b; w.u[2] = c; w.u[3] = d; return w.v;
}
// split p0,p1 into hi-bf16 word and lo-bf16 word
__device__ __forceinline__ void split_words(float p0, float p1, unsigned &wh, unsigned &wl) {
    wh = cvtpk_bf16(p0, p1);
    float h0 = __uint_as_float(wh << 16);
    float h1 = __uint_as_float(wh & 0xffff0000u);
    wl = cvtpk_bf16(p0 - h0, p1 - h1);
}
__device__ __forceinline__ void split_store(float v, u16* ph, u16* pl) {
    __hip_bfloat16 h = __float2bfloat16(v);
    float hf = __bfloat162float(h);
    __hip_bfloat16 l = __float2bfloat16(v - hf);
    *ph = *(u16*)&h;
    *pl = *(u16*)&l;
}
__device__ __forceinline__ short8 ld8(const u16* p) {
    return *(const short8*)p;
}

// ---------------------------------------------------------------------------
// Convert W (fp32 [512][64]) -> transposed hi/lo bf16 [64][512]
// ---------------------------------------------------------------------------
__global__ void convw_kernel(
    const float* __restrict__ Wq, const float* __restrict__ Wk, const float* __restrict__ Wv,
    u16* __restrict__ wqh, u16* __restrict__ wql,
    u16* __restrict__ wkh, u16* __restrict__ wkl,
    u16* __restrict__ wvh, u16* __restrict__ wvl)
{
    const int z = blockIdx.y, chunk = blockIdx.x;
    const float* W = (z == 0) ? Wq : (z == 1) ? Wk : Wv;
    u16* oh = (z == 0) ? wqh : (z == 1) ? wkh : wvh;
    u16* ol = (z == 0) ? wql : (z == 1) ? wkl : wvl;
    const int tid = threadIdx.x;
    #pragma unroll
    for (int i = 0; i < 8; ++i) {
        int idx = tid + i * 256;
        int d = chunk * 32 + (idx >> 6);
        int c = idx & 63;
        float w = W[(size_t)d * 64 + c];
        split_store(w, oh + (size_t)c * 512 + d, ol + (size_t)c * 512 + d);
    }
}

// ---------------------------------------------------------------------------
// QKV projection via split-bf16 MFMA. 1 wave/block, strip of 32 rows,
// all 3 outputs (q scaled; v stored transposed [b][d][4096]).
// ---------------------------------------------------------------------------
__global__ __launch_bounds__(64, 2) void proj_kernel(
    const float* __restrict__ x,
    const u16* __restrict__ wqh, const u16* __restrict__ wql,
    const u16* __restrict__ wkh, const u16* __restrict__ wkl,
    const u16* __restrict__ wvh, const u16* __restrict__ wvl,
    u16* __restrict__ qh, u16* __restrict__ ql,
    u16* __restrict__ kh, u16* __restrict__ kl,
    u16* __restrict__ vth, u16* __restrict__ vtl)
{
    const int strip = blockIdx.x;          // 0..511
    const int t0 = strip * 32;
    const int lane = threadIdx.x;
    const int l31 = lane & 31, hi = lane >> 5;
    f32x16 aq[2] = {{}, {}}, ak[2] = {{}, {}}, av[2] = {{}, {}};
    const float* xrow = x + (size_t)(t0 + l31) * 512;
    #pragma unroll 2
    for (int s = 0; s < 32; ++s) {
        const int d0 = s * 16 + 8 * hi;
        float4 xa = *(const float4*)(xrow + d0);
        float4 xb = *(const float4*)(xrow + d0 + 4);
        unsigned xh_[4], xl_[4];
        split_words(xa.x, xa.y, xh_[0], xl_[0]);
        split_words(xa.z, xa.w, xh_[1], xl_[1]);
        split_words(xb.x, xb.y, xh_[2], xl_[2]);
        split_words(xb.z, xb.w, xh_[3], xl_[3]);
        short8 xhf = mk8(xh_[0], xh_[1], xh_[2], xh_[3]);
        short8 xlf = mk8(xl_[0], xl_[1], xl_[2], xl_[3]);
        #pragma unroll
        for (int half = 0; half < 2; ++half) {
            size_t wof = (size_t)(half * 32 + l31) * 512 + d0;
            short8 qH = ld8(wqh + wof), qL = ld8(wql + wof);
            short8 kH = ld8(wkh + wof), kL = ld8(wkl + wof);
            short8 vH = ld8(wvh + wof), vL = ld8(wvl + wof);
            // q,k: C[t,col]: A=X, B=W
            aq[half] = MFMA(xhf, qH, aq[half]);
            aq[half] = MFMA(xhf, qL, aq[half]);
            aq[half] = MFMA(xlf, qH, aq[half]);
            ak[half] = MFMA(xhf, kH, ak[half]);
            ak[half] = MFMA(xhf, kL, ak[half]);
            ak[half] = MFMA(xlf, kH, ak[half]);
            // v: C[v,t]: A=W^T, B=X^T (same fragments, swapped roles)
            av[half] = MFMA(vH, xhf, av[half]);
            av[half] = MFMA(vL, xhf, av[half]);
            av[half] = MFMA(vH, xlf, av[half]);
        }
    }
    const int b = t0 >> 12;
    const int tin = t0 & 4095;
    #pragma unroll
    for (int half = 0; half < 2; ++half) {
        #pragma unroll
        for (int r = 0; r < 16; ++r) {
            int crow = (r & 3) + 8 * (r >> 2) + 4 * hi;
            int col = half * 32 + l31;
            size_t qo = (size_t)(t0 + crow) * 64 + col;
            split_store(aq[half][r] * 0.125f, qh + qo, ql + qo);
            split_store(ak[half][r], kh + qo, kl + qo);
            size_t vo = ((size_t)b * 64 + half * 32 + crow) * 4096 + tin + l31;
            split_store(av[half][r], vth + vo, vtl + vo);
        }
    }
}

// ---------------------------------------------------------------------------
// Fixup: recompute 16 edge rows/batch with _s weights (fp32), write split.
// ---------------------------------------------------------------------------
__global__ void fixup_kernel(
    const float* __restrict__ x,
    const float* __restrict__ Wqs, const float* __restrict__ Wks, const float* __restrict__ Wvs,
    u16* __restrict__ qh, u16* __restrict__ ql,
    u16* __restrict__ kh, u16* __restrict__ kl,
    u16* __restrict__ vth, u16* __restrict__ vtl)
{
    const int b = blockIdx.x, z = blockIdx.y;
    const float* W = (z == 0) ? Wqs : (z == 1) ? Wks : Wvs;
    const int tid = threadIdx.x;
    #pragma unroll
    for (int k = 0; k < 4; ++k) {
        int idx = tid + k * 256;
        int r = idx >> 6, col = idx & 63;
        int t = (r < 8) ? r : (4080 + r);
        const float* xr = x + ((size_t)b * 4096 + t) * 512;
        float s = 0.f;
        for (int d = 0; d < 512; ++d) s += xr[d] * W[(size_t)d * 64 + col];
        if (z == 0) {
            s *= 0.125f;
            size_t o = ((size_t)b * 4096 + t) * 64 + col;
            split_store(s, qh + o, ql + o);
        } else if (z == 1) {
            size_t o = ((size_t)b * 4096 + t) * 64 + col;
            split_store(s, kh + o, kl + o);
        } else {
            size_t o = ((size_t)b * 64 + col) * 4096 + t;
            split_store(s, vth + o, vtl + o);
        }
    }
}

// ---------------------------------------------------------------------------
// Flash attention, 1 wave/block, 32 q-rows/wave, KV tile 64, split-bf16 MFMA.
// Swapped QK^T (C[k,q]) -> lane-local softmax; P repack via cvt_pk+permlane.
// KV range split into nseg segments; partials merged by merge_kernel.
// ---------------------------------------------------------------------------
__global__ __launch_bounds__(64, 2) void flash_kernel(
    const u16* __restrict__ qhB, const u16* __restrict__ qlB,
    const u16* __restrict__ khB, const u16* __restrict__ klB,
    const u16* __restrict__ vthB, const u16* __restrict__ vtlB,
    float* __restrict__ Opart, float* __restrict__ mpart, float* __restrict__ lpart,
    int nseg)
{
    const int bid = blockIdx.x;
    const int xcd = bid & 7;             // XCD affinity: batch -> XCD pair
    const int b = xcd >> 1, par = xcd & 1;
    const int rr = bid >> 3;
    const int seg = rr % nseg;
    const int hh = rr / nseg;
    const int qw = 127 - (2 * hh + par); // heavy q-blocks first (LPT)
    const int nt = (qw >> 1) + 1;        // causal KV tiles for this q-wave
    const int klo = (nt * seg) / nseg;
    const int khi = (nt * (seg + 1)) / nseg;
    const int lane = threadIdx.x, l31 = lane & 31, hi = lane >> 5;
    const int q0 = qw * 32;

    // Q fragments (B operand: col=q, slots=d)
    const size_t qoff = ((size_t)b * 4096 + q0 + l31) * 64 + 8 * hi;
    short8 qhf[4], qlf[4];
    #pragma unroll
    for (int s = 0; s < 4; ++s) {
        qhf[s] = ld8(qhB + qoff + 16 * s);
        qlf[s] = ld8(qlB + qoff + 16 * s);
    }
    const u16* kh_ = khB + (size_t)b * 4096 * 64;
    const u16* kl_ = klB + (size_t)b * 4096 * 64;
    const u16* vth_ = vthB + (size_t)b * 64 * 4096;
    const u16* vtl_ = vtlB + (size_t)b * 64 * 4096;

    f32x16 o[2] = {{}, {}};
    float mrun = NEG_INF, lrun = 0.f;

    for (int kb = klo; kb < khi; ++kb) {
        const int kk = kb * 64;
        short8 kfh[2][4], kfl[2][4];
        #pragma unroll
        for (int sub = 0; sub < 2; ++sub)
            #pragma unroll
            for (int s = 0; s < 4; ++s) {
                size_t off = (size_t)(kk + 32 * sub + l31) * 64 + 16 * s + 8 * hi;
                kfh[sub][s] = ld8(kh_ + off);
                kfl[sub][s] = ld8(kl_ + off);
            }
        short8 vfh[2][4], vfl[2][4];
        #pragma unroll
        for (int sub = 0; sub < 2; ++sub)
            #pragma unroll
            for (int s = 0; s < 4; ++s) {
                size_t off = (size_t)(sub * 32 + l31) * 4096 + kk + 16 * s + 8 * hi;
                vfh[sub][s] = ld8(vth_ + off);
                vfl[sub][s] = ld8(vtl_ + off);
            }
        // S^T = K @ Q : C[k, q]
        f32x16 c[2] = {{}, {}};
        #pragma unroll
        for (int s = 0; s < 4; ++s) {
            c[0] = MFMA(kfh[0][s], qhf[s], c[0]);
            c[0] = MFMA(kfh[0][s], qlf[s], c[0]);
            c[0] = MFMA(kfl[0][s], qhf[s], c[0]);
            c[1] = MFMA(kfh[1][s], qhf[s], c[1]);
            c[1] = MFMA(kfh[1][s], qlf[s], c[1]);
            c[1] = MFMA(kfl[1][s], qhf[s], c[1]);
        }
        if (kb == nt - 1) {   // diagonal tile: causal mask
            const int qloc = l31 + 32 * (qw & 1);
            #pragma unroll
            for (int r = 0; r < 16; ++r) {
                int krow = (r & 3) + 8 * (r >> 2) + 4 * hi;
                if (krow > qloc) c[0][r] = NEG_INF;
                if (krow + 32 > qloc) c[1][r] = NEG_INF;
            }
        }
        // online softmax (q = l31, lane-local over 32 k + one shfl across halves)
        float mx = NEG_INF;
        #pragma unroll
        for (int r = 0; r < 16; ++r) mx = fmaxf(mx, fmaxf(c[0][r], c[1][r]));
        mx = fmaxf(mx, __shfl_xor(mx, 32));
        float mnew = fmaxf(mrun, mx);
        float alpha = __expf(mrun - mnew);
        mrun = mnew;
        float sum = 0.f;
        #pragma unroll
        for (int r = 0; r < 16; ++r) { c[0][r] = __expf(c[0][r] - mnew); sum += c[0][r]; }
        #pragma unroll
        for (int r = 0; r < 16; ++r) { c[1][r] = __expf(c[1][r] - mnew); sum += c[1][r]; }
        sum += __shfl_xor(sum, 32);
        lrun = lrun * alpha + sum;
        #pragma unroll
        for (int r = 0; r < 16; ++r) { o[0][r] *= alpha; o[1][r] *= alpha; }
        // repack P -> B fragments (hi+lo), k-slot mapping = 16s + 8*hi + j
        short8 pbh[4], pbl[4];
        #pragma unroll
        for (int t = 0; t < 2; ++t) {
            #pragma unroll
            for (int g = 0; g < 2; ++g) {
                unsigned wAh, wAl, wBh, wBl, wCh, wCl, wDh, wDl;
                split_words(c[t][8 * g + 0], c[t][8 * g + 1], wAh, wAl);
                split_words(c[t][8 * g + 2], c[t][8 * g + 3], wBh, wBl);
                split_words(c[t][8 * g + 4], c[t][8 * g + 5], wCh, wCl);
                split_words(c[t][8 * g + 6], c[t][8 * g + 7], wDh, wDl);
                permswap(wAh, wCh); permswap(wBh, wDh);
                permswap(wAl, wCl); permswap(wBl, wDl);
                pbh[2 * t + g] = mk8(wAh, wBh, wCh, wDh);
                pbl[2 * t + g] = mk8(wAl, wBl, wCl, wDl);
            }
        }
        // O^T += V^T @ P^T : C[v, q]
        #pragma unroll
        for (int s = 0; s < 4; ++s) {
            o[0] = MFMA(vfh[0][s], pbh[s], o[0]);
            o[0] = MFMA(vfh[0][s], pbl[s], o[0]);
            o[0] = MFMA(vfl[0][s], pbh[s], o[0]);
            o[1] = MFMA(vfh[1][s], pbh[s], o[1]);
            o[1] = MFMA(vfh[1][s], pbl[s], o[1]);
            o[1] = MFMA(vfl[1][s], pbh[s], o[1]);
        }
    }
    const int pid = (b * 128 + qw) * nseg + seg;
    float* Op = Opart + (size_t)pid * 2048;   // [v][q] layout, coalesced in q
    #pragma unroll
    for (int r = 0; r < 16; ++r) {
        int v0 = (r & 3) + 8 * (r >> 2) + 4 * hi;
        Op[v0 * 32 + l31] = o[0][r];
        Op[(v0 + 32) * 32 + l31] = o[1][r];
    }
    if (hi == 0) {
        mpart[pid * 32 + l31] = mrun;
        lpart[pid * 32 + l31] = lrun;
    }
}

// ---------------------------------------------------------------------------
// Merge nseg partials per q-wave, normalize, write out [b][t][64].
// ---------------------------------------------------------------------------
__global__ void merge_kernel(
    const float* __restrict__ Opart, const float* __restrict__ mpart,
    const float* __restrict__ lpart, float* __restrict__ out, int nseg)
{
    __shared__ float wgt[4][32];
    const int idx = blockIdx.x;   // b*128 + qw
    const int tid = threadIdx.x;
    const int base = idx * nseg;
    if (tid < 32) {
        float M = NEG_INF;
        for (int s = 0; s < nseg; ++s) M = fmaxf(M, mpart[(base + s) * 32 + tid]);
        float L = 0.f;
        for (int s = 0; s < nseg; ++s)
            L += lpart[(base + s) * 32 + tid] * __expf(mpart[(base + s) * 32 + tid] - M);
        float inv = 1.0f / L;
        for (int s = 0; s < nseg; ++s)
            wgt[s][tid] = __expf(mpart[(base + s) * 32 + tid] - M) * inv;
    }
    __syncthreads();
    const int b = idx >> 7, qw = idx & 127;
    float* dst = out + ((size_t)b * 4096 + qw * 32) * 64;
    for (int k = 0; k < 8; ++k) {
        int e = tid + k * 256;
        int q = e >> 6, v = e & 63;
        float acc = 0.f;
        for (int s = 0; s < nseg; ++s)
            acc += wgt[s][q] * Opart[(size_t)(base + s) * 2048 + v * 32 + q];
        dst[q * 64 + v] = acc;
    }
}

extern "C" void kernel_launch(void* const* d_in, const int* in_sizes, int n_in,
                              void* d_out, int out_size, void* d_ws, size_t ws_size,
                              hipStream_t stream) {
    const float* x   = (const float*)d_in[0];
    const float* Wq  = (const float*)d_in[1];
    const float* Wk  = (const float*)d_in[2];
    const float* Wv  = (const float*)d_in[3];
    const float* Wqs = (const float*)d_in[4];
    const float* Wks = (const float*)d_in[5];
    const float* Wvs = (const float*)d_in[6];
    float* out = (float*)d_out;

    char* ws = (char*)d_ws;
    const size_t MB = 1024 * 1024;
    u16* qh  = (u16*)(ws);
    u16* ql  = (u16*)(ws + 2 * MB);
    u16* kh  = (u16*)(ws + 4 * MB);
    u16* kl  = (u16*)(ws + 6 * MB);
    u16* vth = (u16*)(ws + 8 * MB);
    u16* vtl = (u16*)(ws + 10 * MB);
    u16* wqh = (u16*)(ws + 12 * MB);
    u16* wql = (u16*)(ws + 12 * MB + 64 * 1024);
    u16* wkh = (u16*)(ws + 12 * MB + 128 * 1024);
    u16* wkl = (u16*)(ws + 12 * MB + 192 * 1024);
    u16* wvh = (u16*)(ws + 12 * MB + 256 * 1024);
    u16* wvl = (u16*)(ws + 12 * MB + 320 * 1024);
    float* mpart = (float*)(ws + 12 * MB + 384 * 1024);   // up to 256 KB
    float* lpart = (float*)(ws + 12 * MB + 640 * 1024);   // up to 256 KB
    float* Opart = (float*)(ws + 13 * MB);                // up to 16 MB

    // pick segment count by available scratch (13MB + nseg*4MB for Opart)
    int NSEG = 4;
    if (ws_size < 13 * MB + 4 * 4 * MB) NSEG = 2;
    if (ws_size < 13 * MB + 2 * 4 * MB) NSEG = 1;

    convw_kernel<<<dim3(16, 3), 256, 0, stream>>>(Wq, Wk, Wv, wqh, wql, wkh, wkl, wvh, wvl);
    proj_kernel<<<512, 64, 0, stream>>>(x, wqh, wql, wkh, wkl, wvh, wvl,
                                        qh, ql, kh, kl, vth, vtl);
    fixup_kernel<<<dim3(4, 3), 256, 0, stream>>>(x, Wqs, Wks, Wvs,
                                                 qh, ql, kh, kl, vth, vtl);
    flash_kernel<<<512 * NSEG, 64, 0, stream>>>(qh, ql, kh, kl, vth, vtl,
                                                Opart, mpart, lpart, NSEG);
    merge_kernel<<<512, 256, 0, stream>>>(Opart, mpart, lpart, out, NSEG);
}